// Round 1
// baseline (286.980 us; speedup 1.0000x reference)
//
#include <hip/hip_runtime.h>
#include <hip/hip_bf16.h>
#include <stdint.h>

// Transformer-XL relative MHA on MI355X (gfx950), bf16 MFMA pipeline.
// B=2, Q=1024, M=1024, D=1024, H=16, DH=64, K=2048.
// Buffers are fp32 (reference dtypes); checker threshold 1.38e-3.
// Evidence log:
//  - async global_load_lds GEMM staging verified (R5==R6 identity, R7/R8 pass).
//  - R5 failure isolated to bpermute block-selection (banned).
//  - R9/R10: K-split regressed both times; occupancy pinned ~2 blocks/CU
//    regardless of LDS (never the binding limit). Split reverted.
//  - R10 verified: compact-U layout, hvT pre-transpose (kept).
//  - R11: register-prefetch software pipelining in the attn K-loop.
//  - R12 (this): (a) qt complement-remap for b=1 so co-resident block pairs
//    have uniform total work (nt=17+qt imbalance was ~30% CU tail);
//    (b) s_setprio(1) around the compute phase (T5, m191 attn-verified);
//    (c) skip dead tail load/stage/barriers on the last K-tile.

typedef __bf16 bf16;
typedef __bf16 bf16x2 __attribute__((ext_vector_type(2)));
typedef __bf16 bf16x4 __attribute__((ext_vector_type(4)));
typedef __bf16 bf16x8 __attribute__((ext_vector_type(8)));
typedef float  f32x4  __attribute__((ext_vector_type(4)));

// ---------------------------------------------------------------- async copy
__device__ __forceinline__ void async_copy16(void* lds, const void* g) {
    auto gp = (const __attribute__((address_space(1))) void*)(uintptr_t)g;
    auto lp = (__attribute__((address_space(3))) void*)(uint32_t)(uintptr_t)lds;
    __builtin_amdgcn_global_load_lds(gp, lp, 16, 0, 0);
}

// ------------------------------------------------------- 128x128 GEMM core
// C[128,128] = A[m0:+128, :Kd] * Bt[n0:+128, :Kd]^T   (both bf16, K contiguous)
// acc[rb][cb] C-layout: row = m0 + wr + rb*16 + (lane>>4)*4 + reg,
//                       col = n0 + wc + cb*16 + (lane&15)
__device__ __forceinline__ void gemm128_core(
    const bf16* __restrict__ A, const bf16* __restrict__ Bt, const int Kd,
    const int m0, const int n0, bf16* As, bf16* Bs, f32x4 acc[4][4])
{
    const int tid  = threadIdx.x;
    const int lane = tid & 63;
    const int wave = tid >> 6;
    const int wr   = (wave >> 1) * 64;
    const int wc   = (wave & 1) * 64;
    const int lr   = lane & 15;
    const int q4   = lane >> 4;

#pragma unroll
    for (int i = 0; i < 4; ++i)
#pragma unroll
        for (int j = 0; j < 4; ++j) {
            acc[i][j][0] = 0.f; acc[i][j][1] = 0.f; acc[i][j][2] = 0.f; acc[i][j][3] = 0.f;
        }

    for (int k0 = 0; k0 < Kd; k0 += 32) {
#pragma unroll
        for (int it = 0; it < 2; ++it) {
            const int cb0   = (it * 4 + wave) * 64;   // wave-uniform chunk base
            const int chunk = cb0 + lane;
            const int row   = chunk >> 2;
            const int cg    = (chunk & 3) * 8;
            async_copy16(As + cb0 * 8, A  + (size_t)(m0 + row) * Kd + k0 + cg);
            async_copy16(Bs + cb0 * 8, Bt + (size_t)(n0 + row) * Kd + k0 + cg);
        }
        __syncthreads();
        bf16x8 af[4], bfr[4];
#pragma unroll
        for (int rb = 0; rb < 4; ++rb)
            af[rb] = *(const bf16x8*)&As[(wr + rb * 16 + lr) * 32 + q4 * 8];
#pragma unroll
        for (int cb = 0; cb < 4; ++cb)
            bfr[cb] = *(const bf16x8*)&Bs[(wc + cb * 16 + lr) * 32 + q4 * 8];
#pragma unroll
        for (int rb = 0; rb < 4; ++rb)
#pragma unroll
            for (int cb = 0; cb < 4; ++cb)
                acc[rb][cb] = __builtin_amdgcn_mfma_f32_16x16x32_bf16(af[rb], bfr[cb], acc[rb][cb], 0, 0, 0);
        __syncthreads();
    }
}

// ------------------------------------------------------------- prep kernels
__global__ __launch_bounds__(256) void k_tcast(const float* __restrict__ in,
                                               bf16* __restrict__ out, int R, int C)
{
    __shared__ float t[32][33];
    const int c0 = blockIdx.x * 32, r0 = blockIdx.y * 32;
    const int lc = threadIdx.x & 31, lrow = threadIdx.x >> 5;
#pragma unroll
    for (int p = 0; p < 4; ++p)
        t[lrow + p * 8][lc] = in[(size_t)(r0 + lrow + p * 8) * C + c0 + lc];
    __syncthreads();
#pragma unroll
    for (int p = 0; p < 4; ++p)
        out[(size_t)(c0 + lrow + p * 8) * R + r0 + lc] = (bf16)t[lc][lrow + p * 8];
}

__global__ __launch_bounds__(256) void k_cast_cat(const float* __restrict__ mem,
                                                  const float* __restrict__ inp,
                                                  bf16* __restrict__ catb)
{
    const int e   = (blockIdx.x * 256 + threadIdx.x) * 4;
    const int row = e >> 10, dc = e & 1023;
    const int b   = row >> 11, k = row & 2047;
    const float* src = (k < 1024) ? mem + ((size_t)b * 1024 + k) * 1024 + dc
                                  : inp + ((size_t)b * 1024 + (k - 1024)) * 1024 + dc;
    float4 f = *(const float4*)src;
    bf16x4 o; o[0] = (bf16)f.x; o[1] = (bf16)f.y; o[2] = (bf16)f.z; o[3] = (bf16)f.w;
    *(bf16x4*)&catb[e] = o;
}

__global__ __launch_bounds__(256) void k_cast(const float* __restrict__ in,
                                              bf16* __restrict__ out)
{
    const int e = (blockIdx.x * 256 + threadIdx.x) * 4;
    float4 f = *(const float4*)(in + e);
    bf16x4 o; o[0] = (bf16)f.x; o[1] = (bf16)f.y; o[2] = (bf16)f.z; o[3] = (bf16)f.w;
    *(bf16x4*)&out[e] = o;
}

// ---------------------------------------------------------------- QKV GEMM
// hv is written TRANSPOSED per head: hvT[bh][d][k]  (for direct Vt staging)
__global__ __launch_bounds__(256) void k_gemm_qkv(
    const bf16* __restrict__ catb, const bf16* __restrict__ Wt,
    const float* __restrict__ bias, const float* __restrict__ u, const float* __restrict__ v,
    bf16* __restrict__ hq_u, bf16* __restrict__ hq_v,
    bf16* __restrict__ hk, bf16* __restrict__ hvT)
{
    __shared__ bf16 lds[2 * 128 * 32];
    f32x4 acc[4][4];
    const int m0 = blockIdx.x * 128, n0 = blockIdx.y * 128;
    gemm128_core(catb, Wt, 1024, m0, n0, lds, lds + 128 * 32, acc);

    const int lane = threadIdx.x & 63, wave = threadIdx.x >> 6;
    const int wr = (wave >> 1) * 64, wc = (wave & 1) * 64;
    const int lr = lane & 15, q4 = lane >> 4;
#pragma unroll
    for (int rb = 0; rb < 4; ++rb) {
#pragma unroll
        for (int cb = 0; cb < 4; ++cb) {
            const int col  = n0 + wc + cb * 16 + lr;
            const int part = col >> 10;
            const int hd   = col & 1023;
            const int h    = hd >> 6, d = hd & 63;
            const float bcol = bias[col];
#pragma unroll
            for (int r = 0; r < 4; ++r) {
                const int row = m0 + wr + rb * 16 + q4 * 4 + r;
                const int b   = row >> 11, k = row & 2047;
                const float val = acc[rb][cb][r] + bcol;
                if (part == 0) {
                    if (k >= 1024) {
                        const size_t o = (((size_t)(b * 16 + h)) * 1024 + (k - 1024)) * 64 + d;
                        hq_u[o] = (bf16)(val + u[hd]);
                        hq_v[o] = (bf16)(val + v[hd]);
                    }
                } else if (part == 1) {
                    hvT[(((size_t)(b * 16 + h)) * 64 + d) * 2048 + k] = (bf16)val;
                } else {
                    hk[(((size_t)(b * 16 + h)) * 2048 + k) * 64 + d] = (bf16)val;
                }
            }
        }
    }
}

// ------------------------------------------------------------------ R GEMM
__global__ __launch_bounds__(256) void k_gemm_r(
    const bf16* __restrict__ rb_, const bf16* __restrict__ Wt,
    const float* __restrict__ bias, bf16* __restrict__ hr)
{
    __shared__ bf16 lds[2 * 128 * 32];
    f32x4 acc[4][4];
    const int m0 = blockIdx.x * 128, n0 = blockIdx.y * 128;
    gemm128_core(rb_, Wt, 1024, m0, n0, lds, lds + 128 * 32, acc);

    const int lane = threadIdx.x & 63, wave = threadIdx.x >> 6;
    const int wr = (wave >> 1) * 64, wc = (wave & 1) * 64;
    const int lr = lane & 15, q4 = lane >> 4;
#pragma unroll
    for (int rb = 0; rb < 4; ++rb) {
#pragma unroll
        for (int cb = 0; cb < 4; ++cb) {
            const int col = n0 + wc + cb * 16 + lr;
            const int h = col >> 6, d = col & 63;
            const float bcol = bias[col];
#pragma unroll
            for (int r = 0; r < 4; ++r) {
                const int row = m0 + wr + rb * 16 + q4 * 4 + r;
                const int b = row >> 11, k = row & 2047;
                hr[(((size_t)(b * 16 + h)) * 2048 + k) * 64 + d] = (bf16)(acc[rb][cb][r] + bcol);
            }
        }
    }
}

// ---------------------------------------------------------------- out GEMM
__global__ __launch_bounds__(256) void k_gemm_out(
    const bf16* __restrict__ attn, const bf16* __restrict__ Wt,
    const float* __restrict__ bias, float* __restrict__ out)
{
    __shared__ bf16 lds[2 * 128 * 32];
    f32x4 acc[4][4];
    const int m0 = blockIdx.x * 128, n0 = blockIdx.y * 128;
    gemm128_core(attn, Wt, 1024, m0, n0, lds, lds + 128 * 32, acc);

    const int lane = threadIdx.x & 63, wave = threadIdx.x >> 6;
    const int wr = (wave >> 1) * 64, wc = (wave & 1) * 64;
    const int lr = lane & 15, q4 = lane >> 4;
#pragma unroll
    for (int rb = 0; rb < 4; ++rb) {
#pragma unroll
        for (int cb = 0; cb < 4; ++cb) {
            const int col = n0 + wc + cb * 16 + lr;
            const float bcol = bias[col];
#pragma unroll
            for (int r = 0; r < 4; ++r) {
                const int row = m0 + wr + rb * 16 + q4 * 4 + r;
                out[(size_t)row * 1024 + col] = acc[rb][cb][r] + bcol;
            }
        }
    }
}

// -------------------------------------- fused attention, register-pipelined
// One workgroup per (bh, 64-q tile), 64-key tiles. No online max (R8-verified).
// Software pipeline: tile t+1's global loads are issued into registers BEFORE
// computing tile t, so load latency overlaps compute; only ds_writes+barriers
// stay on the critical path. Compact U slab (R10-verified): BD view [16][84],
// Ps view [16][76]. LDS 47616 B.
// R12: qt complement-remap (b=1 flips qt) so the two co-resident blocks per CU
// sum to uniform work; setprio(1) over the compute phase; dead-tail skip.
__global__ __launch_bounds__(256) void k_attn(
    const bf16* __restrict__ hq_u, const bf16* __restrict__ hq_v,
    const bf16* __restrict__ hk, const bf16* __restrict__ hvT,
    const bf16* __restrict__ hr, bf16* __restrict__ attn)
{
    __shared__ bf16 Ks[64][72];        // K tile [k][d]
    __shared__ bf16 Vt[64][72];        // V tile [d][k] (pre-transposed global)
    __shared__ bf16 Rs[128][72];       // R band [j - j0][d]
    __shared__ bf16 U[4][1344];        // per-wave: BD view [16][84] / Ps view [16][76]

    const int bh = blockIdx.y;
    // complement remap: linear block i and i+256 co-reside on a CU; pairing
    // qt with 15-qt makes their total work (17+qt)+(32-qt)=49 uniform.
    const int qt = (bh & 16) ? (15 - (int)blockIdx.x) : (int)blockIdx.x;
    const int q0 = qt * 64;
    const int tid = threadIdx.x, lane = tid & 63, wave = tid >> 6;
    const int lr = lane & 15, q4 = lane >> 4;
    bf16* Uw = &U[wave][0];

    const int nt = 17 + qt;                   // K-tiles for this q-tile
    const size_t kvbase = (size_t)bh * 2048 * 64;

    // fixed per-thread staging coordinates
    const int ci0  = tid,        r0_ = ci0 >> 3,  c0_ = (ci0 & 7) * 8;
    const int ci1  = 256 + tid,  r1_ = ci1 >> 3,  c1_ = (ci1 & 7) * 8;

    // prefetch register loads for tile t
    bf16x8 kv0, kv1, vv0, vv1, rv[4];
    auto load_tile = [&](int t) {
        const int k0 = t * 64;
        kv0 = *(const bf16x8*)&hk [kvbase + (size_t)(k0 + r0_) * 64 + c0_];
        kv1 = *(const bf16x8*)&hk [kvbase + (size_t)(k0 + r1_) * 64 + c1_];
        vv0 = *(const bf16x8*)&hvT[kvbase + (size_t)r0_ * 2048 + k0 + c0_];
        vv1 = *(const bf16x8*)&hvT[kvbase + (size_t)r1_ * 2048 + k0 + c1_];
        const int j0 = k0 + 1024 - q0 - 64;
#pragma unroll
        for (int p = 0; p < 4; ++p) {
            const int ci = p * 256 + tid;
            const int jrow = ci >> 3, cg = (ci & 7) * 8;
            const int j = j0 + jrow;
            bf16x8 val;
#pragma unroll
            for (int z = 0; z < 8; ++z) val[z] = (bf16)0.f;
            if (j < 2048) val = *(const bf16x8*)&hr[kvbase + (size_t)j * 64 + cg];
            rv[p] = val;
        }
    };
    auto write_tile = [&]() {
        *(bf16x8*)&Ks[r0_][c0_] = kv0;
        *(bf16x8*)&Ks[r1_][c1_] = kv1;
        *(bf16x8*)&Vt[r0_][c0_] = vv0;
        *(bf16x8*)&Vt[r1_][c1_] = vv1;
#pragma unroll
        for (int p = 0; p < 4; ++p) {
            const int ci = p * 256 + tid;
            *(bf16x8*)&Rs[ci >> 3][(ci & 7) * 8] = rv[p];
        }
    };

    // Q fragments (A-operand layout: m = lane&15, k = (lane>>4)*8 + j)
    const size_t qrow = ((size_t)bh * 1024 + q0 + wave * 16 + lr) * 64;
    const bf16x8 qu0 = *(const bf16x8*)&hq_u[qrow + q4 * 8];
    const bf16x8 qu1 = *(const bf16x8*)&hq_u[qrow + 32 + q4 * 8];
    const bf16x8 qv0 = *(const bf16x8*)&hq_v[qrow + q4 * 8];
    const bf16x8 qv1 = *(const bf16x8*)&hq_v[qrow + 32 + q4 * 8];

    f32x4 Oacc[4];
#pragma unroll
    for (int i = 0; i < 4; ++i) { Oacc[i][0] = 0.f; Oacc[i][1] = 0.f; Oacc[i][2] = 0.f; Oacc[i][3] = 0.f; }
    float lp[4] = {0.f, 0.f, 0.f, 0.f};

    // prologue: stage tile 0
    load_tile(0);
    write_tile();
    __syncthreads();

    for (int t = 0; t < nt; ++t) {
        const int k0 = t * 64;
        const bool more = (t + 1 < nt);
        // issue next tile's global loads NOW (overlap with compute below)
        if (more) load_tile(t + 1);

        __builtin_amdgcn_s_setprio(1);
        // ---- AC = (hq+u) @ K^T
        f32x4 S[4];
#pragma unroll
        for (int cb = 0; cb < 4; ++cb) {
            const bf16x8 kf0 = *(const bf16x8*)&Ks[cb * 16 + lr][q4 * 8];
            const bf16x8 kf1 = *(const bf16x8*)&Ks[cb * 16 + lr][32 + q4 * 8];
            f32x4 z; z[0] = 0.f; z[1] = 0.f; z[2] = 0.f; z[3] = 0.f;
            z = __builtin_amdgcn_mfma_f32_16x16x32_bf16(qu0, kf0, z, 0, 0, 0);
            S[cb] = __builtin_amdgcn_mfma_f32_16x16x32_bf16(qu1, kf1, z, 0, 0, 0);
        }
        // ---- BD band -> compact LDS view (stride 84, col jbi*16+lr)
#pragma unroll
        for (int jbi = 0; jbi < 5; ++jbi) {
            const int jb = jbi + 3 - wave;
            const bf16x8 rf0 = *(const bf16x8*)&Rs[jb * 16 + lr][q4 * 8];
            const bf16x8 rf1 = *(const bf16x8*)&Rs[jb * 16 + lr][32 + q4 * 8];
            f32x4 z; z[0] = 0.f; z[1] = 0.f; z[2] = 0.f; z[3] = 0.f;
            z = __builtin_amdgcn_mfma_f32_16x16x32_bf16(qv0, rf0, z, 0, 0, 0);
            z = __builtin_amdgcn_mfma_f32_16x16x32_bf16(qv1, rf1, z, 0, 0, 0);
#pragma unroll
            for (int r = 0; r < 4; ++r) Uw[(q4 * 4 + r) * 84 + jbi * 16 + lr] = (bf16)z[r];
        }

        // ---- read ALL shifted BD values into registers (before Ps writes)
        float bdv[4][4];
#pragma unroll
        for (int cb = 0; cb < 4; ++cb)
#pragma unroll
            for (int r = 0; r < 4; ++r) {
                const int tq = q4 * 4 + r;
                bdv[cb][r] = (float)Uw[tq * 84 + cb * 16 + lr + 15 - tq];
            }

        // ---- scores: mask, exp (no max), accumulate l, Ps write (stride 76)
#pragma unroll
        for (int cb = 0; cb < 4; ++cb) {
            const int k = k0 + cb * 16 + lr;
#pragma unroll
            for (int r = 0; r < 4; ++r) {
                const int q = q0 + wave * 16 + q4 * 4 + r;
                const float s = (S[cb][r] + bdv[cb][r]) * 0.125f;
                const float p = (k <= 1024 + q) ? __expf(s) : 0.f;
                lp[r] += p;
                Uw[(q4 * 4 + r) * 76 + cb * 16 + lr] = (bf16)p;   // Ps view
            }
        }

        // ---- PV: P (A-layout via Ps view) @ V
        const bf16x8 pf0 = *(const bf16x8*)&Uw[lr * 76 + q4 * 8];
        const bf16x8 pf1 = *(const bf16x8*)&Uw[lr * 76 + 32 + q4 * 8];
#pragma unroll
        for (int db = 0; db < 4; ++db) {
            const bf16x8 vf0 = *(const bf16x8*)&Vt[db * 16 + lr][q4 * 8];
            const bf16x8 vf1 = *(const bf16x8*)&Vt[db * 16 + lr][32 + q4 * 8];
            Oacc[db] = __builtin_amdgcn_mfma_f32_16x16x32_bf16(pf0, vf0, Oacc[db], 0, 0, 0);
            Oacc[db] = __builtin_amdgcn_mfma_f32_16x16x32_bf16(pf1, vf1, Oacc[db], 0, 0, 0);
        }
        __builtin_amdgcn_s_setprio(0);

        if (more) {
            __syncthreads();           // everyone done reading tile t
            write_tile();              // stage tile t+1 from prefetched regs
            __syncthreads();           // tile t+1 visible
        }
    }

    // ---- 16-lane row-sum of l, normalize, write
#pragma unroll
    for (int off = 1; off < 16; off <<= 1)
#pragma unroll
        for (int r = 0; r < 4; ++r) lp[r] += __shfl_xor(lp[r], off, 64);

    const int b = bh >> 4, h = bh & 15;
#pragma unroll
    for (int r = 0; r < 4; ++r) {
        const float rl = 1.f / lp[r];
        const int q = q0 + wave * 16 + q4 * 4 + r;
#pragma unroll
        for (int db = 0; db < 4; ++db) {
            const int d = db * 16 + lr;
            attn[(((size_t)b * 1024 + q) * 16 + h) * 64 + d] = (bf16)(Oacc[db][r] * rl);
        }
    }
}

// ------------------------------------------------------------------ launch
extern "C" void kernel_launch(void* const* d_in, const int* in_sizes, int n_in,
                              void* d_out, int out_size, void* d_ws, size_t ws_size,
                              hipStream_t stream)
{
    const float* inputs = (const float*)d_in[0];
    const float* mem    = (const float*)d_in[1];
    const float* r      = (const float*)d_in[2];
    const float* W_qkv  = (const float*)d_in[3];
    const float* b_qkv  = (const float*)d_in[4];
    const float* W_r    = (const float*)d_in[5];
    const float* b_r    = (const float*)d_in[6];
    const float* W_o    = (const float*)d_in[7];
    const float* b_o    = (const float*)d_in[8];
    const float* u      = (const float*)d_in[9];
    const float* v      = (const float*)d_in[10];
    float* out = (float*)d_out;

    char* ws = (char*)d_ws;
    size_t off = 0;
    auto alloc = [&](size_t bytes) -> void* {
        void* p = ws + off;
        off += (bytes + 255) & ~(size_t)255;
        return p;
    };
    bf16* hq_u  = (bf16*)alloc(2ull * 16 * 1024 * 64 * 2);
    bf16* hq_v  = (bf16*)alloc(2ull * 16 * 1024 * 64 * 2);
    bf16* hk    = (bf16*)alloc(2ull * 16 * 2048 * 64 * 2);
    bf16* hvT   = (bf16*)alloc(2ull * 16 * 2048 * 64 * 2);
    bf16* hr    = (bf16*)alloc(2ull * 16 * 2048 * 64 * 2);
    bf16* attnb = (bf16*)alloc(2ull * 1024 * 1024 * 2);
    bf16* Wot   = (bf16*)alloc(1024ull * 1024 * 2);
    bf16* catb  = (bf16*)alloc(4096ull * 1024 * 2);
    bf16* rb    = (bf16*)alloc(4096ull * 1024 * 2);
    bf16* Wqkvt = (bf16*)alloc(3072ull * 1024 * 2);
    bf16* Wrt   = (bf16*)alloc(1024ull * 1024 * 2);

    k_tcast<<<dim3(96, 32), 256, 0, stream>>>(W_qkv, Wqkvt, 1024, 3072);
    k_tcast<<<dim3(32, 32), 256, 0, stream>>>(W_r, Wrt, 1024, 1024);
    k_tcast<<<dim3(32, 32), 256, 0, stream>>>(W_o, Wot, 1024, 1024);
    k_cast_cat<<<4096, 256, 0, stream>>>(mem, inputs, catb);
    k_cast<<<4096, 256, 0, stream>>>(r, rb);

    k_gemm_qkv<<<dim3(32, 24), 256, 0, stream>>>(catb, Wqkvt, b_qkv, u, v, hq_u, hq_v, hk, hvT);
    k_gemm_r<<<dim3(32, 8), 256, 0, stream>>>(rb, Wrt, b_r, hr);
    k_attn<<<dim3(16, 32), 256, 0, stream>>>(hq_u, hq_v, hk, hvT, hr, attnb);
    k_gemm_out<<<dim3(16, 8), 256, 0, stream>>>(attnb, Wot, b_o, out);
}

// Round 3
// 272.303 us; speedup vs baseline: 1.0539x; 1.0539x over previous
//
#include <hip/hip_runtime.h>
#include <hip/hip_bf16.h>
#include <stdint.h>

// Transformer-XL relative MHA on MI355X (gfx950), bf16 MFMA pipeline.
// B=2, Q=1024, M=1024, D=1024, H=16, DH=64, K=2048.
// Buffers are fp32 (reference dtypes); checker threshold 1.38e-3.
// Evidence log:
//  - async global_load_lds GEMM staging verified (R5==R6 identity, R7/R8 pass).
//  - R5 failure isolated to bpermute block-selection (banned).
//  - R9/R10: K-split regressed both times; occupancy pinned ~2 blocks/CU.
//  - R10 verified: compact-U layout, hvT pre-transpose (kept).
//  - R11: register-prefetch software pipelining in the attn K-loop.
//  - R12: qt complement-remap; setprio over compute; dead-tail skip.
//    Result 305->287 us; k_attn 83 us, MfmaUtil 10%, VALU 31%, all pipes idle
//    => serialization-bound (2 barriers/tile, redundant R staging).
//  - R13 (re-submitted; R2 lease timed out before bench): (a) rolling 3-slot
//    R window (192 rows): only 64 NEW R rows staged per tile (halves R
//    global+LDS traffic); (b) K/V double-buffer + single end-of-iteration
//    barrier (hazard-checked: iter-t writes disjoint from iter-t reads);
//    (c) fuse qkv+r GEMMs into one 1024-block dispatch.

typedef __bf16 bf16;
typedef __bf16 bf16x2 __attribute__((ext_vector_type(2)));
typedef __bf16 bf16x4 __attribute__((ext_vector_type(4)));
typedef __bf16 bf16x8 __attribute__((ext_vector_type(8)));
typedef float  f32x4  __attribute__((ext_vector_type(4)));

// ---------------------------------------------------------------- async copy
__device__ __forceinline__ void async_copy16(void* lds, const void* g) {
    auto gp = (const __attribute__((address_space(1))) void*)(uintptr_t)g;
    auto lp = (__attribute__((address_space(3))) void*)(uint32_t)(uintptr_t)lds;
    __builtin_amdgcn_global_load_lds(gp, lp, 16, 0, 0);
}

// ------------------------------------------------------- 128x128 GEMM core
// C[128,128] = A[m0:+128, :Kd] * Bt[n0:+128, :Kd]^T   (both bf16, K contiguous)
// acc[rb][cb] C-layout: row = m0 + wr + rb*16 + (lane>>4)*4 + reg,
//                       col = n0 + wc + cb*16 + (lane&15)
__device__ __forceinline__ void gemm128_core(
    const bf16* __restrict__ A, const bf16* __restrict__ Bt, const int Kd,
    const int m0, const int n0, bf16* As, bf16* Bs, f32x4 acc[4][4])
{
    const int tid  = threadIdx.x;
    const int lane = tid & 63;
    const int wave = tid >> 6;
    const int wr   = (wave >> 1) * 64;
    const int wc   = (wave & 1) * 64;
    const int lr   = lane & 15;
    const int q4   = lane >> 4;

#pragma unroll
    for (int i = 0; i < 4; ++i)
#pragma unroll
        for (int j = 0; j < 4; ++j) {
            acc[i][j][0] = 0.f; acc[i][j][1] = 0.f; acc[i][j][2] = 0.f; acc[i][j][3] = 0.f;
        }

    for (int k0 = 0; k0 < Kd; k0 += 32) {
#pragma unroll
        for (int it = 0; it < 2; ++it) {
            const int cb0   = (it * 4 + wave) * 64;   // wave-uniform chunk base
            const int chunk = cb0 + lane;
            const int row   = chunk >> 2;
            const int cg    = (chunk & 3) * 8;
            async_copy16(As + cb0 * 8, A  + (size_t)(m0 + row) * Kd + k0 + cg);
            async_copy16(Bs + cb0 * 8, Bt + (size_t)(n0 + row) * Kd + k0 + cg);
        }
        __syncthreads();
        bf16x8 af[4], bfr[4];
#pragma unroll
        for (int rb = 0; rb < 4; ++rb)
            af[rb] = *(const bf16x8*)&As[(wr + rb * 16 + lr) * 32 + q4 * 8];
#pragma unroll
        for (int cb = 0; cb < 4; ++cb)
            bfr[cb] = *(const bf16x8*)&Bs[(wc + cb * 16 + lr) * 32 + q4 * 8];
#pragma unroll
        for (int rb = 0; rb < 4; ++rb)
#pragma unroll
            for (int cb = 0; cb < 4; ++cb)
                acc[rb][cb] = __builtin_amdgcn_mfma_f32_16x16x32_bf16(af[rb], bfr[cb], acc[rb][cb], 0, 0, 0);
        __syncthreads();
    }
}

// ------------------------------------------------------------- prep kernels
__global__ __launch_bounds__(256) void k_tcast(const float* __restrict__ in,
                                               bf16* __restrict__ out, int R, int C)
{
    __shared__ float t[32][33];
    const int c0 = blockIdx.x * 32, r0 = blockIdx.y * 32;
    const int lc = threadIdx.x & 31, lrow = threadIdx.x >> 5;
#pragma unroll
    for (int p = 0; p < 4; ++p)
        t[lrow + p * 8][lc] = in[(size_t)(r0 + lrow + p * 8) * C + c0 + lc];
    __syncthreads();
#pragma unroll
    for (int p = 0; p < 4; ++p)
        out[(size_t)(c0 + lrow + p * 8) * R + r0 + lc] = (bf16)t[lc][lrow + p * 8];
}

__global__ __launch_bounds__(256) void k_cast_cat(const float* __restrict__ mem,
                                                  const float* __restrict__ inp,
                                                  bf16* __restrict__ catb)
{
    const int e   = (blockIdx.x * 256 + threadIdx.x) * 4;
    const int row = e >> 10, dc = e & 1023;
    const int b   = row >> 11, k = row & 2047;
    const float* src = (k < 1024) ? mem + ((size_t)b * 1024 + k) * 1024 + dc
                                  : inp + ((size_t)b * 1024 + (k - 1024)) * 1024 + dc;
    float4 f = *(const float4*)src;
    bf16x4 o; o[0] = (bf16)f.x; o[1] = (bf16)f.y; o[2] = (bf16)f.z; o[3] = (bf16)f.w;
    *(bf16x4*)&catb[e] = o;
}

__global__ __launch_bounds__(256) void k_cast(const float* __restrict__ in,
                                              bf16* __restrict__ out)
{
    const int e = (blockIdx.x * 256 + threadIdx.x) * 4;
    float4 f = *(const float4*)(in + e);
    bf16x4 o; o[0] = (bf16)f.x; o[1] = (bf16)f.y; o[2] = (bf16)f.z; o[3] = (bf16)f.w;
    *(bf16x4*)&out[e] = o;
}

// ------------------------------------------------- fused QKV + R GEMM
// blockIdx.y in [0,24): QKV GEMM (catb @ Wqkvt), epilogue scatters q/k/v.
// blockIdx.y in [24,32): R GEMM (rb @ Wrt), epilogue writes hr.
// hv is written TRANSPOSED per head: hvT[bh][d][k]  (for direct Vt staging)
__global__ __launch_bounds__(256) void k_gemm_qkvr(
    const bf16* __restrict__ catb, const bf16* __restrict__ Wqkvt,
    const float* __restrict__ b_qkv, const float* __restrict__ u, const float* __restrict__ v,
    const bf16* __restrict__ rb_, const bf16* __restrict__ Wrt,
    const float* __restrict__ b_r,
    bf16* __restrict__ hq_u, bf16* __restrict__ hq_v,
    bf16* __restrict__ hk, bf16* __restrict__ hvT, bf16* __restrict__ hr)
{
    __shared__ bf16 lds[2 * 128 * 32];
    f32x4 acc[4][4];
    const int m0 = blockIdx.x * 128;
    const int lane = threadIdx.x & 63, wave = threadIdx.x >> 6;
    const int wr = (wave >> 1) * 64, wc = (wave & 1) * 64;
    const int lr = lane & 15, q4 = lane >> 4;

    if (blockIdx.y < 24) {
        const int n0 = blockIdx.y * 128;
        gemm128_core(catb, Wqkvt, 1024, m0, n0, lds, lds + 128 * 32, acc);
#pragma unroll
        for (int rb = 0; rb < 4; ++rb) {
#pragma unroll
            for (int cb = 0; cb < 4; ++cb) {
                const int col  = n0 + wc + cb * 16 + lr;
                const int part = col >> 10;
                const int hd   = col & 1023;
                const int h    = hd >> 6, d = hd & 63;
                const float bcol = b_qkv[col];
#pragma unroll
                for (int r = 0; r < 4; ++r) {
                    const int row = m0 + wr + rb * 16 + q4 * 4 + r;
                    const int b   = row >> 11, k = row & 2047;
                    const float val = acc[rb][cb][r] + bcol;
                    if (part == 0) {
                        if (k >= 1024) {
                            const size_t o = (((size_t)(b * 16 + h)) * 1024 + (k - 1024)) * 64 + d;
                            hq_u[o] = (bf16)(val + u[hd]);
                            hq_v[o] = (bf16)(val + v[hd]);
                        }
                    } else if (part == 1) {
                        hvT[(((size_t)(b * 16 + h)) * 64 + d) * 2048 + k] = (bf16)val;
                    } else {
                        hk[(((size_t)(b * 16 + h)) * 2048 + k) * 64 + d] = (bf16)val;
                    }
                }
            }
        }
    } else {
        const int n0 = (blockIdx.y - 24) * 128;
        gemm128_core(rb_, Wrt, 1024, m0, n0, lds, lds + 128 * 32, acc);
#pragma unroll
        for (int rb = 0; rb < 4; ++rb) {
#pragma unroll
            for (int cb = 0; cb < 4; ++cb) {
                const int col = n0 + wc + cb * 16 + lr;
                const int h = col >> 6, d = col & 63;
                const float bcol = b_r[col];
#pragma unroll
                for (int r = 0; r < 4; ++r) {
                    const int row = m0 + wr + rb * 16 + q4 * 4 + r;
                    const int b = row >> 11, k = row & 2047;
                    hr[(((size_t)(b * 16 + h)) * 2048 + k) * 64 + d] = (bf16)(acc[rb][cb][r] + bcol);
                }
            }
        }
    }
}

// ---------------------------------------------------------------- out GEMM
__global__ __launch_bounds__(256) void k_gemm_out(
    const bf16* __restrict__ attn, const bf16* __restrict__ Wt,
    const float* __restrict__ bias, float* __restrict__ out)
{
    __shared__ bf16 lds[2 * 128 * 32];
    f32x4 acc[4][4];
    const int m0 = blockIdx.x * 128, n0 = blockIdx.y * 128;
    gemm128_core(attn, Wt, 1024, m0, n0, lds, lds + 128 * 32, acc);

    const int lane = threadIdx.x & 63, wave = threadIdx.x >> 6;
    const int wr = (wave >> 1) * 64, wc = (wave & 1) * 64;
    const int lr = lane & 15, q4 = lane >> 4;
#pragma unroll
    for (int rb = 0; rb < 4; ++rb) {
#pragma unroll
        for (int cb = 0; cb < 4; ++cb) {
            const int col = n0 + wc + cb * 16 + lr;
            const float bcol = bias[col];
#pragma unroll
            for (int r = 0; r < 4; ++r) {
                const int row = m0 + wr + rb * 16 + q4 * 4 + r;
                out[(size_t)row * 1024 + col] = acc[rb][cb][r] + bcol;
            }
        }
    }
}

// -------------------------------------- fused attention, single-barrier
// One workgroup per (bh, 64-q tile), 64-key tiles. No online max (R8-verified).
// R13 structure:
//  - K/V double-buffered LDS (Ks/Vt[2]); compute reads buf=t&1, stage writes
//    buf^1 => iter-t writes never touch iter-t read regions.
//  - R rolling window Rs[192] = 3 chunks of 64 rows. Tile t reads chunks
//    mt, mt+1 (slots mt%3,(mt+1)%3); stage writes chunk mt+2 (third slot).
//    Only 64 NEW R rows loaded per tile (band overlap exploited).
//  - ONE __syncthreads per tile (write->barrier->next-read ordering; all
//    concurrent write/read region pairs disjoint by construction).
// LDS: Ks 18432 + Vt 18432 + Rs 27648 + U 10752 = 75264 B => 2 blocks/CU.
__global__ __launch_bounds__(256) void k_attn(
    const bf16* __restrict__ hq_u, const bf16* __restrict__ hq_v,
    const bf16* __restrict__ hk, const bf16* __restrict__ hvT,
    const bf16* __restrict__ hr, bf16* __restrict__ attn)
{
    __shared__ bf16 Ks[2][64][72];     // K tile [k][d], double-buffered
    __shared__ bf16 Vt[2][64][72];     // V tile [d][k], double-buffered
    __shared__ bf16 Rs[192 * 72];      // R rolling window: 3 slots x 64 rows
    __shared__ bf16 U[4][1344];        // per-wave: BD view [16][84] / Ps view [16][76]

    const int bh = blockIdx.y;
    // complement remap: linear block i and i+256 co-reside on a CU; pairing
    // qt with 15-qt makes their total work (17+qt)+(32-qt)=49 uniform.
    const int qt = (bh & 16) ? (15 - (int)blockIdx.x) : (int)blockIdx.x;
    const int q0 = qt * 64;
    const int tid = threadIdx.x, lane = tid & 63, wave = tid >> 6;
    const int lr = lane & 15, q4 = lane >> 4;
    bf16* Uw = &U[wave][0];

    const int nt  = 17 + qt;                  // K-tiles for this q-tile
    const int m0c = 15 - qt;                  // base R-chunk index at t=0
    const size_t kvbase = (size_t)bh * 2048 * 64;

    // fixed per-thread staging coordinates (64 rows x 64 cols per tile/chunk)
    const int ci0  = tid,        r0_ = ci0 >> 3,  c0_ = (ci0 & 7) * 8;
    const int ci1  = 256 + tid,  r1_ = ci1 >> 3,  c1_ = (ci1 & 7) * 8;

    // prefetch registers
    bf16x8 kv0, kv1, vv0, vv1, rv0, rv1;
    auto load_kv = [&](int t) {
        const int k0 = t * 64;
        kv0 = *(const bf16x8*)&hk [kvbase + (size_t)(k0 + r0_) * 64 + c0_];
        kv1 = *(const bf16x8*)&hk [kvbase + (size_t)(k0 + r1_) * 64 + c1_];
        vv0 = *(const bf16x8*)&hvT[kvbase + (size_t)r0_ * 2048 + k0 + c0_];
        vv1 = *(const bf16x8*)&hvT[kvbase + (size_t)r1_ * 2048 + k0 + c1_];
    };
    auto load_r = [&](int c) {               // R chunk c: global rows [64c, 64c+64)
        if (c * 64 < 2048) {
            rv0 = *(const bf16x8*)&hr[kvbase + (size_t)(c * 64 + r0_) * 64 + c0_];
            rv1 = *(const bf16x8*)&hr[kvbase + (size_t)(c * 64 + r1_) * 64 + c1_];
        } else {
#pragma unroll
            for (int z = 0; z < 8; ++z) { rv0[z] = (bf16)0.f; rv1[z] = (bf16)0.f; }
        }
    };
    auto write_kv = [&](int buf) {
        *(bf16x8*)&Ks[buf][r0_][c0_] = kv0;
        *(bf16x8*)&Ks[buf][r1_][c1_] = kv1;
        *(bf16x8*)&Vt[buf][r0_][c0_] = vv0;
        *(bf16x8*)&Vt[buf][r1_][c1_] = vv1;
    };
    auto write_r = [&](int slot) {
        *(bf16x8*)&Rs[(slot * 64 + r0_) * 72 + c0_] = rv0;
        *(bf16x8*)&Rs[(slot * 64 + r1_) * 72 + c1_] = rv1;
    };

    // Q fragments (A-operand layout: m = lane&15, k = (lane>>4)*8 + j)
    const size_t qrow = ((size_t)bh * 1024 + q0 + wave * 16 + lr) * 64;
    const bf16x8 qu0 = *(const bf16x8*)&hq_u[qrow + q4 * 8];
    const bf16x8 qu1 = *(const bf16x8*)&hq_u[qrow + 32 + q4 * 8];
    const bf16x8 qv0 = *(const bf16x8*)&hq_v[qrow + q4 * 8];
    const bf16x8 qv1 = *(const bf16x8*)&hq_v[qrow + 32 + q4 * 8];

    f32x4 Oacc[4];
#pragma unroll
    for (int i = 0; i < 4; ++i) { Oacc[i][0] = 0.f; Oacc[i][1] = 0.f; Oacc[i][2] = 0.f; Oacc[i][3] = 0.f; }
    float lp[4] = {0.f, 0.f, 0.f, 0.f};

    // prologue: stage K/V tile 0 + R chunks m0c, m0c+1
    load_kv(0);  write_kv(0);
    load_r(m0c);     write_r(m0c % 3);
    load_r(m0c + 1); write_r((m0c + 1) % 3);
    __syncthreads();

    for (int t = 0; t < nt; ++t) {
        const int k0  = t * 64;
        const int mt  = m0c + t;
        const int s0  = mt % 3;
        const int s1  = (s0 + 1 == 3) ? 0 : s0 + 1;
        const int s2  = (s1 + 1 == 3) ? 0 : s1 + 1;
        const int buf = t & 1;
        const bool more = (t + 1 < nt);
        // issue next tile's global loads NOW (overlap with compute below)
        if (more) { load_kv(t + 1); load_r(mt + 2); }

        __builtin_amdgcn_s_setprio(1);
        // ---- AC = (hq+u) @ K^T
        f32x4 S[4];
#pragma unroll
        for (int cb = 0; cb < 4; ++cb) {
            const bf16x8 kf0 = *(const bf16x8*)&Ks[buf][cb * 16 + lr][q4 * 8];
            const bf16x8 kf1 = *(const bf16x8*)&Ks[buf][cb * 16 + lr][32 + q4 * 8];
            f32x4 z; z[0] = 0.f; z[1] = 0.f; z[2] = 0.f; z[3] = 0.f;
            z = __builtin_amdgcn_mfma_f32_16x16x32_bf16(qu0, kf0, z, 0, 0, 0);
            S[cb] = __builtin_amdgcn_mfma_f32_16x16x32_bf16(qu1, kf1, z, 0, 0, 0);
        }
        // ---- BD band -> compact LDS view (stride 84, col jbi*16+lr)
#pragma unroll
        for (int jbi = 0; jbi < 5; ++jbi) {
            const int jb   = jbi + 3 - wave;              // 0..7
            const int rrow = ((jb & 4) ? s1 : s0) * 64 + (jb & 3) * 16 + lr;
            const bf16x8 rf0 = *(const bf16x8*)&Rs[rrow * 72 + q4 * 8];
            const bf16x8 rf1 = *(const bf16x8*)&Rs[rrow * 72 + 32 + q4 * 8];
            f32x4 z; z[0] = 0.f; z[1] = 0.f; z[2] = 0.f; z[3] = 0.f;
            z = __builtin_amdgcn_mfma_f32_16x16x32_bf16(qv0, rf0, z, 0, 0, 0);
            z = __builtin_amdgcn_mfma_f32_16x16x32_bf16(qv1, rf1, z, 0, 0, 0);
#pragma unroll
            for (int r = 0; r < 4; ++r) Uw[(q4 * 4 + r) * 84 + jbi * 16 + lr] = (bf16)z[r];
        }

        // ---- read ALL shifted BD values into registers (before Ps writes)
        float bdv[4][4];
#pragma unroll
        for (int cb = 0; cb < 4; ++cb)
#pragma unroll
            for (int r = 0; r < 4; ++r) {
                const int tq = q4 * 4 + r;
                bdv[cb][r] = (float)Uw[tq * 84 + cb * 16 + lr + 15 - tq];
            }

        // ---- scores: mask, exp (no max), accumulate l, Ps write (stride 76)
#pragma unroll
        for (int cb = 0; cb < 4; ++cb) {
            const int k = k0 + cb * 16 + lr;
#pragma unroll
            for (int r = 0; r < 4; ++r) {
                const int q = q0 + wave * 16 + q4 * 4 + r;
                const float s = (S[cb][r] + bdv[cb][r]) * 0.125f;
                const float p = (k <= 1024 + q) ? __expf(s) : 0.f;
                lp[r] += p;
                Uw[(q4 * 4 + r) * 76 + cb * 16 + lr] = (bf16)p;   // Ps view
            }
        }

        // ---- PV: P (A-layout via Ps view) @ V
        const bf16x8 pf0 = *(const bf16x8*)&Uw[lr * 76 + q4 * 8];
        const bf16x8 pf1 = *(const bf16x8*)&Uw[lr * 76 + 32 + q4 * 8];
#pragma unroll
        for (int db = 0; db < 4; ++db) {
            const bf16x8 vf0 = *(const bf16x8*)&Vt[buf][db * 16 + lr][q4 * 8];
            const bf16x8 vf1 = *(const bf16x8*)&Vt[buf][db * 16 + lr][32 + q4 * 8];
            Oacc[db] = __builtin_amdgcn_mfma_f32_16x16x32_bf16(pf0, vf0, Oacc[db], 0, 0, 0);
            Oacc[db] = __builtin_amdgcn_mfma_f32_16x16x32_bf16(pf1, vf1, Oacc[db], 0, 0, 0);
        }
        __builtin_amdgcn_s_setprio(0);

        if (more) {
            // stage tile t+1 into the OTHER buffer / third R slot: disjoint
            // from everything read this iteration => no pre-write barrier.
            write_kv(buf ^ 1);
            write_r(s2);
            __syncthreads();           // make staged tile visible to all waves
        }
    }

    // ---- 16-lane row-sum of l, normalize, write
#pragma unroll
    for (int off = 1; off < 16; off <<= 1)
#pragma unroll
        for (int r = 0; r < 4; ++r) lp[r] += __shfl_xor(lp[r], off, 64);

    const int b = bh >> 4, h = bh & 15;
#pragma unroll
    for (int r = 0; r < 4; ++r) {
        const float rl = 1.f / lp[r];
        const int q = q0 + wave * 16 + q4 * 4 + r;
#pragma unroll
        for (int db = 0; db < 4; ++db) {
            const int d = db * 16 + lr;
            attn[(((size_t)b * 1024 + q) * 16 + h) * 64 + d] = (bf16)(Oacc[db][r] * rl);
        }
    }
}

// ------------------------------------------------------------------ launch
extern "C" void kernel_launch(void* const* d_in, const int* in_sizes, int n_in,
                              void* d_out, int out_size, void* d_ws, size_t ws_size,
                              hipStream_t stream)
{
    const float* inputs = (const float*)d_in[0];
    const float* mem    = (const float*)d_in[1];
    const float* r      = (const float*)d_in[2];
    const float* W_qkv  = (const float*)d_in[3];
    const float* b_qkv  = (const float*)d_in[4];
    const float* W_r    = (const float*)d_in[5];
    const float* b_r    = (const float*)d_in[6];
    const float* W_o    = (const float*)d_in[7];
    const float* b_o    = (const float*)d_in[8];
    const float* u      = (const float*)d_in[9];
    const float* v      = (const float*)d_in[10];
    float* out = (float*)d_out;

    char* ws = (char*)d_ws;
    size_t off = 0;
    auto alloc = [&](size_t bytes) -> void* {
        void* p = ws + off;
        off += (bytes + 255) & ~(size_t)255;
        return p;
    };
    bf16* hq_u  = (bf16*)alloc(2ull * 16 * 1024 * 64 * 2);
    bf16* hq_v  = (bf16*)alloc(2ull * 16 * 1024 * 64 * 2);
    bf16* hk    = (bf16*)alloc(2ull * 16 * 2048 * 64 * 2);
    bf16* hvT   = (bf16*)alloc(2ull * 16 * 2048 * 64 * 2);
    bf16* hr    = (bf16*)alloc(2ull * 16 * 2048 * 64 * 2);
    bf16* attnb = (bf16*)alloc(2ull * 1024 * 1024 * 2);
    bf16* Wot   = (bf16*)alloc(1024ull * 1024 * 2);
    bf16* catb  = (bf16*)alloc(4096ull * 1024 * 2);
    bf16* rb    = (bf16*)alloc(4096ull * 1024 * 2);
    bf16* Wqkvt = (bf16*)alloc(3072ull * 1024 * 2);
    bf16* Wrt   = (bf16*)alloc(1024ull * 1024 * 2);

    k_tcast<<<dim3(96, 32), 256, 0, stream>>>(W_qkv, Wqkvt, 1024, 3072);
    k_tcast<<<dim3(32, 32), 256, 0, stream>>>(W_r, Wrt, 1024, 1024);
    k_tcast<<<dim3(32, 32), 256, 0, stream>>>(W_o, Wot, 1024, 1024);
    k_cast_cat<<<4096, 256, 0, stream>>>(mem, inputs, catb);
    k_cast<<<4096, 256, 0, stream>>>(r, rb);

    k_gemm_qkvr<<<dim3(32, 32), 256, 0, stream>>>(catb, Wqkvt, b_qkv, u, v,
                                                  rb, Wrt, b_r,
                                                  hq_u, hq_v, hk, hvT, hr);
    k_attn<<<dim3(16, 32), 256, 0, stream>>>(hq_u, hq_v, hk, hvT, hr, attnb);
    k_gemm_out<<<dim3(16, 8), 256, 0, stream>>>(attnb, Wot, b_o, out);
}